// Round 1
// baseline (419.808 us; speedup 1.0000x reference)
//
#include <hip/hip_runtime.h>
#include <hip/hip_bf16.h>
#include <stdint.h>

typedef unsigned short u16;
typedef __attribute__((ext_vector_type(8))) short bf16x8;
typedef __attribute__((ext_vector_type(4))) float f32x4;

#define DEV static __device__ __forceinline__

DEV u16 f2bf(float f){
  union { float f; unsigned u; } x; x.f = f;
  unsigned r = x.u + 0x7fffu + ((x.u >> 16) & 1u);
  return (u16)(r >> 16);
}

DEV void g2l16(const void* g, void* l){
  __builtin_amdgcn_global_load_lds((const __attribute__((address_space(1))) unsigned int*)g,
                                   (__attribute__((address_space(3))) unsigned int*)l,
                                   16, 0, 0);
}

// ---------------- f32 -> bf16 straight convert ----------------
__global__ __launch_bounds__(256)
void f2bf_k(const float* __restrict__ in, u16* __restrict__ out){
  int idx = blockIdx.x*256 + threadIdx.x;
  float4 v = *(const float4*)&in[(size_t)idx*4];
  u16 a = f2bf(v.x), b = f2bf(v.y), c = f2bf(v.z), d = f2bf(v.w);
  ushort4 o4; o4.x=a; o4.y=b; o4.z=c; o4.w=d;
  *(ushort4*)&out[(size_t)idx*4] = o4;
}

// ---------------- f32 [R][C] -> bf16 [C][R] transpose ----------------
__global__ __launch_bounds__(256)
void transp_k(const float* __restrict__ in, u16* __restrict__ out, int R, int C){
  __shared__ float tile[32][33];
  const int c0 = blockIdx.x*32, r0 = blockIdx.y*32;
  const int x = threadIdx.x & 31, y0 = threadIdx.x >> 5;
#pragma unroll
  for (int j=0;j<4;j++){
    int r = y0 + j*8;
    tile[r][x] = in[(size_t)(r0+r)*C + c0 + x];
  }
  __syncthreads();
#pragma unroll
  for (int j=0;j<4;j++){
    int cc = y0 + j*8;
    out[(size_t)(c0+cc)*R + r0 + x] = f2bf(tile[x][cc]);
  }
}

// ---------------- bf16 GEMM: A[M,K] (row, lda), B^T[N,K] (row, ldb) -> C[M,N] ----------------
template<bool OBF>
__global__ __launch_bounds__(256)
void gemm_k(const u16* __restrict__ A, const u16* __restrict__ B, void* __restrict__ Cp,
            int K, int lda, int ldb, int ldc){
  __shared__ u16 As[128*32];
  __shared__ u16 Bs[128*32];
  const int m0 = blockIdx.y*128, n0 = blockIdx.x*128;
  const int tid = threadIdx.x;
  const int lane = tid & 63, wave = tid >> 6;
  const int wr = wave >> 1, wc = wave & 1;
  const int lr = lane & 15, kg = lane >> 4;
  const f32x4 vzero = {0.f,0.f,0.f,0.f};
  f32x4 acc[4][4];
#pragma unroll
  for (int a=0;a<4;a++)
#pragma unroll
    for (int b=0;b<4;b++) acc[a][b] = vzero;
  const int r0 = tid>>2, s0 = tid&3;
  for (int k0=0;k0<K;k0+=32){
    __syncthreads();
    g2l16(A + (size_t)(m0+r0)*lda + k0 + s0*8, (u16*)As + (size_t)tid*8);
    g2l16(B + (size_t)(n0+r0)*ldb + k0 + s0*8, (u16*)Bs + (size_t)tid*8);
    g2l16(A + (size_t)(m0+r0+64)*lda + k0 + s0*8, (u16*)As + (size_t)(tid+256)*8);
    g2l16(B + (size_t)(n0+r0+64)*ldb + k0 + s0*8, (u16*)Bs + (size_t)(tid+256)*8);
    __syncthreads();
    bf16x8 af[4], bfv[4];
#pragma unroll
    for (int mi=0;mi<4;mi++) af[mi]  = *(const bf16x8*)(As + (wr*64+mi*16+lr)*32 + kg*8);
#pragma unroll
    for (int ni=0;ni<4;ni++) bfv[ni] = *(const bf16x8*)(Bs + (wc*64+ni*16+lr)*32 + kg*8);
#pragma unroll
    for (int mi=0;mi<4;mi++)
#pragma unroll
      for (int ni=0;ni<4;ni++)
        acc[mi][ni] = __builtin_amdgcn_mfma_f32_16x16x32_bf16(af[mi], bfv[ni], acc[mi][ni], 0, 0, 0);
  }
#pragma unroll
  for (int mi=0;mi<4;mi++)
#pragma unroll
    for (int ni=0;ni<4;ni++)
#pragma unroll
      for (int vv=0;vv<4;vv++){
        int row = m0 + wr*64 + mi*16 + kg*4 + vv;
        int col = n0 + wc*64 + ni*16 + lr;
        float val = acc[mi][ni][vv];
        if (OBF) ((u16*)Cp)[(size_t)row*ldc + col] = f2bf(val);
        else     ((float*)Cp)[(size_t)row*ldc + col] = val;
      }
}

// ---------------- beta = sigmoid(h @ Wb), per-t block ----------------
__global__ __launch_bounds__(256)
void beta_k(const float* __restrict__ h, const float* __restrict__ Wb, float* __restrict__ betab){
  __shared__ float hrow[2048];
  __shared__ float red[16][5];
  const int t = blockIdx.x, tid = threadIdx.x;
#pragma unroll
  for (int j=0;j<8;j++) hrow[tid + j*256] = h[(size_t)t*2048 + tid + j*256];
  __syncthreads();
  float part[16];
#pragma unroll
  for (int n=0;n<16;n++) part[n]=0.f;
  for (int j=0;j<8;j++){
    int kk = tid + j*256;
    float hv = hrow[kk];
    const float4* wr4 = (const float4*)&Wb[(size_t)kk*16];
    float4 w0=wr4[0], w1=wr4[1], w2=wr4[2], w3=wr4[3];
    part[0]+=hv*w0.x; part[1]+=hv*w0.y; part[2]+=hv*w0.z; part[3]+=hv*w0.w;
    part[4]+=hv*w1.x; part[5]+=hv*w1.y; part[6]+=hv*w1.z; part[7]+=hv*w1.w;
    part[8]+=hv*w2.x; part[9]+=hv*w2.y; part[10]+=hv*w2.z; part[11]+=hv*w2.w;
    part[12]+=hv*w3.x; part[13]+=hv*w3.y; part[14]+=hv*w3.z; part[15]+=hv*w3.w;
  }
#pragma unroll
  for (int n=0;n<16;n++){
    float s = part[n];
#pragma unroll
    for (int off=1;off<64;off<<=1) s += __shfl_xor(s, off);
    if ((tid&63)==0) red[n][tid>>6] = s;
  }
  __syncthreads();
  if (tid < 16){
    float s = red[tid][0]+red[tid][1]+red[tid][2]+red[tid][3];
    betab[t*16+tid] = 1.f/(1.f+__expf(-s));
  }
}

// ---------------- causal conv4 + silu on concatenated qkvw ----------------
__global__ __launch_bounds__(256)
void conv_k(const float* __restrict__ raw, const float* __restrict__ cq,
            const float* __restrict__ ck, const float* __restrict__ cv,
            float* __restrict__ qo, float* __restrict__ ko,
            float* __restrict__ vo, float* __restrict__ wo){
  int idx = blockIdx.x*256 + threadIdx.x;
  int cgl = idx & 8191, tb = idx >> 13;
  int which = cgl >> 11, cc = cgl & 2047;
  const float* wt = (which==0)?cq:((which==1)?ck:cv);   // w-branch (3) uses cv (faithful to ref)
  float4 w4 = *(const float4*)&wt[cc*4];
  float* out = (which==0)?qo:((which==1)?ko:((which==2)?vo:wo));
  int t0 = tb*4;
  float x[7];
#pragma unroll
  for (int j=0;j<7;j++){
    int t = t0 - 3 + j;
    x[j] = (t >= 0) ? raw[(size_t)t*8192 + cgl] : 0.f;
  }
#pragma unroll
  for (int j=0;j<4;j++){
    float y = x[j]*w4.x + x[j+1]*w4.y + x[j+2]*w4.z + x[j+3]*w4.w;
    y = y / (1.f + __expf(-y));           // silu
    out[(size_t)(t0+j)*2048 + cc] = y;
  }
}

// ---------------- l2norm over M + beta scale: bw ----------------
__global__ __launch_bounds__(256)
void l2bw_k(const float* __restrict__ wconv, const float* __restrict__ betab,
            float* __restrict__ bwout){
  int row = blockIdx.x*4 + (threadIdx.x>>6);
  int lane = threadIdx.x & 63;
  int t = row >> 4, h = row & 15;
  size_t base = (size_t)t*2048 + h*128;
  float a0 = wconv[base+lane], a1 = wconv[base+64+lane];
  float ss = a0*a0 + a1*a1;
#pragma unroll
  for (int off=1;off<64;off<<=1) ss += __shfl_xor(ss, off);
  float r = rsqrtf(ss + 1e-6f) * betab[t*16+h];
  bwout[base+lane]    = a0*r;
  bwout[base+64+lane] = a1*r;
}

// ---------------- per-chunk inclusive cumsum of logsigmoid(gpre) ----------------
__global__ __launch_bounds__(256)
void cg_k(const float* __restrict__ gpre, float* __restrict__ cg){
  int idx = blockIdx.x*256 + threadIdx.x;   // 32768 = c*2048 + h*128 + m
  int m = idx & 127, h = (idx>>7) & 15, c = idx >> 11;
  size_t base = (size_t)h*128 + m;
  float run = 0.f;
  for (int i2=0;i2<64;i2++){
    size_t t = (size_t)c*64 + i2;
    float x = gpre[t*2048 + base];
    float lg = (x >= 0.f) ? (-log1pf(__expf(-x))) : (x - log1pf(__expf(x)));
    run += lg;
    cg[t*2048 + base] = run;
  }
}

// ---------------- Phase A: per-chunk state deltas ----------------
__global__ __launch_bounds__(256)
void phaseA_k(const float* __restrict__ k, const float* __restrict__ v,
              const float* __restrict__ bw, const float* __restrict__ cg,
              float* __restrict__ DSk, float* __restrict__ DSv){
  __shared__ float Ks[64][132];
  __shared__ float Vs[64][132];
  __shared__ float Us[64][132];
  __shared__ float Gt[128];
  const int bx=blockIdx.x, h=bx&15, c=bx>>4, tid=threadIdx.x;
  if (tid < 128) Gt[tid] = cg[(size_t)(c*64+63)*2048 + h*128 + tid];
#pragma unroll
  for (int j=0;j<8;j++){
    int f4=tid+j*256, r=f4>>5, c4=(f4&31)<<2;
    size_t g=(size_t)(c*64+r)*2048 + h*128 + c4;
    *(float4*)&Ks[r][c4] = *(const float4*)&k[g];
    *(float4*)&Vs[r][c4] = *(const float4*)&v[g];
  }
  __syncthreads();
#pragma unroll
  for (int j=0;j<8;j++){
    int f4=tid+j*256, r=f4>>5, c4=(f4&31)<<2;
    size_t g=(size_t)(c*64+r)*2048 + h*128 + c4;
    float4 bv=*(const float4*)&bw[g];
    float4 cgv=*(const float4*)&cg[g];
    float4 u;
    u.x=bv.x*__expf(Gt[c4+0]-cgv.x);
    u.y=bv.y*__expf(Gt[c4+1]-cgv.y);
    u.z=bv.z*__expf(Gt[c4+2]-cgv.z);
    u.w=bv.w*__expf(Gt[c4+3]-cgv.w);
    *(float4*)&Us[r][c4]=u;
  }
  __syncthreads();
  const int d = tid>>1, p = tid&1;
  for (int mq=0;mq<4;mq++){
    float acc[16];
#pragma unroll
    for (int j=0;j<16;j++) acc[j]=0.f;
    for (int s=0;s<64;s++){
      float kv = Ks[s][d];
#pragma unroll
      for (int j=0;j<4;j++){
        float4 u4 = *(float4*)&Us[s][mq*32+p*16+(j<<2)];
        acc[j*4+0]+=kv*u4.x; acc[j*4+1]+=kv*u4.y; acc[j*4+2]+=kv*u4.z; acc[j*4+3]+=kv*u4.w;
      }
    }
    size_t ob = ((size_t)bx*128 + d)*128 + mq*32 + p*16;
#pragma unroll
    for (int j=0;j<4;j++){
      float4 st = {acc[j*4+0],acc[j*4+1],acc[j*4+2],acc[j*4+3]};
      *(float4*)&DSk[ob+(j<<2)] = st;
    }
  }
  const int m = tid>>1;
  for (int vq=0;vq<4;vq++){
    float acc[16];
#pragma unroll
    for (int j=0;j<16;j++) acc[j]=0.f;
    for (int s=0;s<64;s++){
      float uv = Us[s][m];
#pragma unroll
      for (int j=0;j<4;j++){
        float4 v4 = *(float4*)&Vs[s][vq*32+p*16+(j<<2)];
        acc[j*4+0]+=uv*v4.x; acc[j*4+1]+=uv*v4.y; acc[j*4+2]+=uv*v4.z; acc[j*4+3]+=uv*v4.w;
      }
    }
    size_t ob = ((size_t)bx*128 + m)*128 + vq*32 + p*16;
#pragma unroll
    for (int j=0;j<4;j++){
      float4 st = {acc[j*4+0],acc[j*4+1],acc[j*4+2],acc[j*4+3]};
      *(float4*)&DSv[ob+(j<<2)] = st;
    }
  }
}

// ---------------- Phase B: sequential cross-chunk state combine ----------------
__global__ __launch_bounds__(256)
void phaseB_k(const float* __restrict__ DSk, const float* __restrict__ DSv,
              const float* __restrict__ cg, float* __restrict__ Sk0, float* __restrict__ Sv0){
  unsigned idx = blockIdx.x*256u + threadIdx.x;   // 524288 total
  int sel  = idx >> 18;
  int h    = (idx >> 14) & 15;
  int flat = idx & 16383;                 // d*128+m (Sk) or m*128+v (Sv)
  int mdec = sel ? (flat >> 7) : (flat & 127);
  const float* DS = sel ? DSv : DSk;
  float* S = sel ? Sv0 : Sk0;
  float cur = 0.f;
  for (int c=0;c<16;c++){
    size_t sb = ((size_t)(c*16+h))*16384 + flat;
    S[sb] = cur;                           // state BEFORE chunk c
    float gd = __expf(cg[(size_t)(c*64+63)*2048 + h*128 + mdec]);
    cur = cur*gd + DS[sb];
  }
}

// ---------------- Phase C: per-chunk outputs ----------------
__global__ __launch_bounds__(256)
void phaseC_k(const float* __restrict__ q, const float* __restrict__ k,
              const float* __restrict__ v, const float* __restrict__ bw,
              const float* __restrict__ cg, const float* __restrict__ Sk0,
              const float* __restrict__ Sv0, float* __restrict__ o){
  __shared__ float Qs[64][132];   // Q, later A'
  __shared__ float Ks[64][132];   // K, later V
  __shared__ float Bws[64][132];  // bw * e^{cgm - cg_s}
  __shared__ float Ss[64][68];    // sqk, later P (masked)
  __shared__ float St[32][132];   // Sk'/Sv' staging tiles
  __shared__ float cgm[128];
  __shared__ float ecgm[128];
  const int bx = blockIdx.x, h = bx&15, c = bx>>4;
  const int tid = threadIdx.x;
  const int i = tid>>2, qq = tid&3;
  const float SCALE = 0.088388347648318447f;   // 128^-0.5
  if (tid < 128){
    float cv_ = cg[(size_t)(c*64+31)*2048 + h*128 + tid];
    cgm[tid] = cv_; ecgm[tid] = __expf(cv_);
  }
  __syncthreads();
#pragma unroll
  for (int j=0;j<8;j++){
    int f4=tid+j*256, r=f4>>5, c4=(f4&31)<<2;
    size_t g=(size_t)(c*64+r)*2048 + h*128 + c4;
    *(float4*)&Qs[r][c4] = *(const float4*)&q[g];
    *(float4*)&Ks[r][c4] = *(const float4*)&k[g];
  }
  float dec[32];
  {
    size_t g0 = (size_t)(c*64+i)*2048 + h*128 + qq*32;
#pragma unroll
    for (int j4=0;j4<8;j4++){
      float4 cgv = *(const float4*)&cg[g0 + (j4<<2)];
      float4 bwv = *(const float4*)&bw[g0 + (j4<<2)];
      float d0 = cgm[qq*32+j4*4+0]-cgv.x, d1 = cgm[qq*32+j4*4+1]-cgv.y;
      float d2 = cgm[qq*32+j4*4+2]-cgv.z, d3 = cgm[qq*32+j4*4+3]-cgv.w;
      Bws[i][qq*32+j4*4+0]=bwv.x*__expf(d0);
      Bws[i][qq*32+j4*4+1]=bwv.y*__expf(d1);
      Bws[i][qq*32+j4*4+2]=bwv.z*__expf(d2);
      Bws[i][qq*32+j4*4+3]=bwv.w*__expf(d3);
      dec[j4*4+0]=__expf(-d0); dec[j4*4+1]=__expf(-d1);
      dec[j4*4+2]=__expf(-d2); dec[j4*4+3]=__expf(-d3);
    }
  }
  __syncthreads();
  // step1: sqk[i][s] = q_i . k_s (masked s<=i)
  {
    float a16[16];
#pragma unroll
    for (int jj=0;jj<16;jj++) a16[jj]=0.f;
    for (int d4=0; d4<32; ++d4){
      float4 qv = *(float4*)&Qs[i][d4<<2];
#pragma unroll
      for (int jj=0;jj<16;jj++){
        float4 kv = *(float4*)&Ks[qq*16+jj][d4<<2];
        a16[jj] += qv.x*kv.x + qv.y*kv.y + qv.z*kv.z + qv.w*kv.w;
      }
    }
#pragma unroll
    for (int jj=0;jj<16;jj++){
      int s = qq*16+jj;
      Ss[i][s] = (s<=i) ? a16[jj] : 0.f;
    }
  }
  __syncthreads();
  // step2: z = Q @ (Sk_start * e^{cgm[m]})
  float z[32];
#pragma unroll
  for (int j=0;j<32;j++) z[j]=0.f;
  for (int dt=0; dt<4; ++dt){
    if (dt) __syncthreads();
#pragma unroll
    for (int j=0;j<4;j++){
      int f4=tid+j*256, r=f4>>5, c4=(f4&31)<<2;
      float4 sv0 = *(const float4*)&Sk0[(size_t)bx*16384 + (size_t)(dt*32+r)*128 + c4];
      float4 e;
      e.x=sv0.x*ecgm[c4+0]; e.y=sv0.y*ecgm[c4+1]; e.z=sv0.z*ecgm[c4+2]; e.w=sv0.w*ecgm[c4+3];
      *(float4*)&St[r][c4] = e;
    }
    __syncthreads();
    for (int dd=0; dd<32; ++dd){
      float qd = Qs[i][dt*32+dd];
#pragma unroll
      for (int j8=0;j8<8;j8++){
        float4 s4 = *(float4*)&St[dd][qq*32+(j8<<2)];
        z[j8*4+0]+=qd*s4.x; z[j8*4+1]+=qd*s4.y; z[j8*4+2]+=qd*s4.z; z[j8*4+3]+=qd*s4.w;
      }
    }
  }
  // step3: z += tril(sqk) @ Bws ; s = SCALE*dec*z ; softmax over m
  for (int s=0;s<64;s++){
    float p = Ss[i][s];
#pragma unroll
    for (int j8=0;j8<8;j8++){
      float4 b4 = *(float4*)&Bws[s][qq*32+(j8<<2)];
      z[j8*4+0]+=p*b4.x; z[j8*4+1]+=p*b4.y; z[j8*4+2]+=p*b4.z; z[j8*4+3]+=p*b4.w;
    }
  }
  float mx = -3.0e38f;
#pragma unroll
  for (int j=0;j<32;j++){ z[j] = SCALE*dec[j]*z[j]; mx = fmaxf(mx, z[j]); }
  mx = fmaxf(mx, __shfl_xor(mx,1)); mx = fmaxf(mx, __shfl_xor(mx,2));
  float ssum = 0.f;
#pragma unroll
  for (int j=0;j<32;j++){ z[j] = __expf(z[j]-mx); ssum += z[j]; }
  ssum += __shfl_xor(ssum,1); ssum += __shfl_xor(ssum,2);
  float inv = 1.f/ssum;
#pragma unroll
  for (int j=0;j<32;j++) Qs[i][qq*32+j] = z[j]*inv*dec[j];   // A' = a * e^{cg_i - cgm}
  __syncthreads();
  // step4: P[i][s] = A'[i,:] . Bws[s,:]  (masked)
  {
    float a16[16];
#pragma unroll
    for (int jj=0;jj<16;jj++) a16[jj]=0.f;
    for (int m4=0;m4<32;m4++){
      float4 av = *(float4*)&Qs[i][m4<<2];
#pragma unroll
      for (int jj=0;jj<16;jj++){
        float4 b4 = *(float4*)&Bws[qq*16+jj][m4<<2];
        a16[jj] += av.x*b4.x + av.y*b4.y + av.z*b4.z + av.w*b4.w;
      }
    }
#pragma unroll
    for (int jj=0;jj<16;jj++){
      int s = qq*16+jj;
      Ss[i][s] = (s<=i) ? a16[jj] : 0.f;
    }
  }
  // restage V into Ks (K dead since step1; step1 finished block-wide via step-2 barriers)
#pragma unroll
  for (int j=0;j<8;j++){
    int f4=tid+j*256, r=f4>>5, c4=(f4&31)<<2;
    *(float4*)&Ks[r][c4] = *(const float4*)&v[(size_t)(c*64+r)*2048 + h*128 + c4];
  }
  __syncthreads();
  // step5: o = P @ V
#pragma unroll
  for (int j=0;j<32;j++) z[j]=0.f;
  for (int s=0;s<64;s++){
    float p = Ss[i][s];
#pragma unroll
    for (int j8=0;j8<8;j8++){
      float4 v4 = *(float4*)&Ks[s][qq*32+(j8<<2)];
      z[j8*4+0]+=p*v4.x; z[j8*4+1]+=p*v4.y; z[j8*4+2]+=p*v4.z; z[j8*4+3]+=p*v4.w;
    }
  }
  // step6: o += A' @ (e^{cgm[m]} * Sv_start)
  for (int mt=0; mt<4; ++mt){
    __syncthreads();
#pragma unroll
    for (int j=0;j<4;j++){
      int f4=tid+j*256, r=f4>>5, c4=(f4&31)<<2;
      float4 sv0 = *(const float4*)&Sv0[(size_t)bx*16384 + (size_t)(mt*32+r)*128 + c4];
      float em = ecgm[mt*32+r];
      float4 e = {sv0.x*em, sv0.y*em, sv0.z*em, sv0.w*em};
      *(float4*)&St[r][c4] = e;
    }
    __syncthreads();
    for (int mm=0;mm<32;mm++){
      float a = Qs[i][mt*32+mm];
#pragma unroll
      for (int j8=0;j8<8;j8++){
        float4 s4 = *(float4*)&St[mm][qq*32+(j8<<2)];
        z[j8*4+0]+=a*s4.x; z[j8*4+1]+=a*s4.y; z[j8*4+2]+=a*s4.z; z[j8*4+3]+=a*s4.w;
      }
    }
  }
  size_t ob = (size_t)(c*64+i)*2048 + h*128 + qq*32;
#pragma unroll
  for (int j8=0;j8<8;j8++){
    float4 ov = {z[j8*4+0], z[j8*4+1], z[j8*4+2], z[j8*4+3]};
    *(float4*)&o[ob+(j8<<2)] = ov;
  }
}

// ---------------- gated RMSNorm -> bf16 ----------------
__global__ __launch_bounds__(256)
void norm_k(const float* __restrict__ o, const float* __restrict__ gate,
            const float* __restrict__ bg2, const float* __restrict__ nw,
            u16* __restrict__ Obf){
  int row = blockIdx.x*4 + (threadIdx.x>>6);
  int lane = threadIdx.x & 63;
  int t = row >> 4, h = row & 15;
  size_t base = (size_t)t*2048 + h*128;
  float o0 = o[base+lane], o1 = o[base+64+lane];
  float ss = o0*o0 + o1*o1;
#pragma unroll
  for (int off=1;off<64;off<<=1) ss += __shfl_xor(ss, off);
  float r = rsqrtf(ss*(1.f/128.f) + 1e-5f);
  int hv0 = h*128+lane, hv1 = hv0+64;
  float g0 = gate[base+lane]    + bg2[hv0];
  float g1 = gate[base+64+lane] + bg2[hv1];
  float v0 = o0*r*nw[lane]   *(1.f/(1.f+__expf(-g0)));
  float v1 = o1*r*nw[lane+64]*(1.f/(1.f+__expf(-g1)));
  Obf[base+lane]    = f2bf(v0);
  Obf[base+64+lane] = f2bf(v1);
}

extern "C" void kernel_launch(void* const* d_in, const int* in_sizes, int n_in,
                              void* d_out, int out_size, void* d_ws, size_t ws_size,
                              hipStream_t stream){
  (void)in_sizes; (void)n_in; (void)out_size; (void)ws_size;
  const float* hX   = (const float*)d_in[0];
  const float* Wq   = (const float*)d_in[1];
  const float* Wk   = (const float*)d_in[2];
  const float* Wv   = (const float*)d_in[3];
  const float* Ww   = (const float*)d_in[4];
  const float* cq   = (const float*)d_in[5];
  const float* ck   = (const float*)d_in[6];
  const float* cv   = (const float*)d_in[7];
  const float* Wf1  = (const float*)d_in[8];
  const float* Wf2  = (const float*)d_in[9];
  const float* Wb   = (const float*)d_in[10];
  const float* Wg1  = (const float*)d_in[11];
  const float* Wg2  = (const float*)d_in[12];
  const float* bg2  = (const float*)d_in[13];
  const float* nw   = (const float*)d_in[14];
  const float* Wo   = (const float*)d_in[15];
  char* ws = (char*)d_ws;
  u16*   h_bf  = (u16*)  (ws + 0);
  u16*   WcatT = (u16*)  (ws + 4194304);
  float* Sk0   = (float*)(ws + 4194304);            // reuses WcatT after G1
  float* Sv0   = (float*)(ws + 4194304 + 16777216);
  u16*   WoT   = (u16*)  (ws + 37748736);
  u16*   WfgT  = (u16*)  (ws + 46137344);
  u16*   Wf2T  = (u16*)  (ws + 47185920);
  u16*   Wg2T  = (u16*)  (ws + 47710208);
  float* qkvw  = (float*)(ws + 48234496);
  float* DSk   = (float*)(ws + 48234496);           // reuses qkvw after conv
  float* DSv   = (float*)(ws + 48234496 + 16777216);
  float* qb    = (float*)(ws + 81788928);
  float* kb    = (float*)(ws + 90177536);
  float* vb    = (float*)(ws + 98566144);
  float* wcv   = (float*)(ws + 106954752);
  float* osc   = wcv;                               // reuses wconv after l2bw
  float* bwb   = (float*)(ws + 115343360);
  u16*   f1g1  = (u16*)  (ws + 123731968);
  float* gpre  = (float*)(ws + 124256256);
  float* gateb = gpre;                              // reuses gpre after cg
  float* cgb   = (float*)(ws + 132644864);
  float* betab = (float*)(ws + 141033472);
  u16*   Obf   = (u16*)  (ws + 141099008);
  float* outp  = (float*)d_out;

  // conversions
  f2bf_k<<<2048,256,0,stream>>>(hX, h_bf);
  transp_k<<<dim3(64,64),256,0,stream>>>(Wq, WcatT + (size_t)0*2048*2048, 2048, 2048);
  transp_k<<<dim3(64,64),256,0,stream>>>(Wk, WcatT + (size_t)1*2048*2048, 2048, 2048);
  transp_k<<<dim3(64,64),256,0,stream>>>(Wv, WcatT + (size_t)2*2048*2048, 2048, 2048);
  transp_k<<<dim3(64,64),256,0,stream>>>(Ww, WcatT + (size_t)3*2048*2048, 2048, 2048);
  transp_k<<<dim3(64,64),256,0,stream>>>(Wo, WoT, 2048, 2048);
  transp_k<<<dim3(4,64), 256,0,stream>>>(Wf1, WfgT, 2048, 128);
  transp_k<<<dim3(4,64), 256,0,stream>>>(Wg1, WfgT + (size_t)128*2048, 2048, 128);
  transp_k<<<dim3(64,4), 256,0,stream>>>(Wf2, Wf2T, 128, 2048);
  transp_k<<<dim3(64,4), 256,0,stream>>>(Wg2, Wg2T, 128, 2048);

  // projections
  gemm_k<false><<<dim3(64,8),256,0,stream>>>(h_bf, WcatT, qkvw, 2048, 2048, 2048, 8192);
  gemm_k<true ><<<dim3(2,8), 256,0,stream>>>(h_bf, WfgT, f1g1, 2048, 2048, 2048, 256);
  gemm_k<false><<<dim3(16,8),256,0,stream>>>(f1g1, Wf2T, gpre, 128, 256, 128, 2048);
  beta_k<<<1024,256,0,stream>>>(hX, Wb, betab);

  // conv + silu, l2norm*beta, chunk cumsum of logsigmoid
  conv_k<<<8192,256,0,stream>>>(qkvw, cq, ck, cv, qb, kb, vb, wcv);
  l2bw_k<<<4096,256,0,stream>>>(wcv, betab, bwb);
  cg_k<<<128,256,0,stream>>>(gpre, cgb);

  // gate GEMM (into gpre buffer, safe after cg)
  gemm_k<false><<<dim3(16,8),256,0,stream>>>(f1g1 + 128, Wg2T, gateb, 128, 256, 128, 2048);

  // chunked scan
  phaseA_k<<<256,256,0,stream>>>(kb, vb, bwb, cgb, DSk, DSv);
  phaseB_k<<<2048,256,0,stream>>>(DSk, DSv, cgb, Sk0, Sv0);
  phaseC_k<<<256,256,0,stream>>>(qb, kb, vb, bwb, cgb, Sk0, Sv0, osc);

  // gated RMSNorm + output projection
  norm_k<<<4096,256,0,stream>>>(osc, gateb, bg2, nw, Obf);
  gemm_k<false><<<dim3(16,8),256,0,stream>>>(Obf, WoT, outp, 2048, 2048, 2048, 2048);
}